// Round 2
// baseline (4006.559 us; speedup 1.0000x reference)
//
#include <hip/hip_runtime.h>

typedef unsigned short u16;
typedef unsigned int u32;
typedef __attribute__((ext_vector_type(8))) short bf16x8;
typedef __attribute__((ext_vector_type(4))) float f32x4;

#define T_STEPS 512
#define BATCH 256
#define FEAT 128
#define H1 200
#define G1 800          // 4*H1
#define G1P 832         // padded to 52*16
#define KP 224          // H1 padded to 7*32
#define NW 64           // workgroups in main kernel
#define BS 4            // batch rows per WG

__device__ __forceinline__ u16 f2bf(float x) {
    u32 u = __float_as_uint(x);
    u = (u + 0x7fffu + ((u >> 16) & 1u)) >> 16;
    return (u16)u;
}
__device__ __forceinline__ float bfu2f(u32 u) { return __uint_as_float(u << 16); }

__device__ __forceinline__ float sigf(float x) {
    return __builtin_amdgcn_rcpf(1.f + __expf(-x));
}
__device__ __forceinline__ float tanhf_fast(float x) {
    return 1.f - 2.f * __builtin_amdgcn_rcpf(1.f + __expf(2.f * x));
}

// ---------------------------------------------------------------------------
// Kernel 1: repack weights to bf16 MFMA B-fragment order + fused bias
//   whhf: [(wv*13+nt)*7+kt][lane][8]   (n = 16*nti + (l&15), k = kt*32+(l>>4)*8+j)
//   wihf: [ntg*4+kt][lane][8]
//   b1p : b_ih1+b_hh1 padded to 832
// Gate columns are RAW weight-row indices: i=0..199, f=200..399, g=400..599,
// o=600..799 (contiguous, NO per-gate padding).
// ---------------------------------------------------------------------------
__global__ void repack_k(const float* __restrict__ wih1, const float* __restrict__ whh1,
                         const float* __restrict__ bih1, const float* __restrict__ bhh1,
                         u16* __restrict__ wihf, u16* __restrict__ whhf, float* __restrict__ b1p) {
    int id = blockIdx.x * 256 + threadIdx.x;
    if (id < G1P) b1p[id] = (id < G1) ? (bih1[id] + bhh1[id]) : 0.f;
    if (id < 23296) { // 52*7*64 lane-slots for whh
        int l = id & 63, fi = id >> 6;
        int kt = fi % 7, nti = fi / 7;
        int n = nti * 16 + (l & 15);
        int kb = kt * 32 + (l >> 4) * 8;
        u16 o[8];
#pragma unroll
        for (int j = 0; j < 8; ++j) {
            int k = kb + j;
            float v = (n < G1 && k < H1) ? whh1[n * H1 + k] : 0.f;
            o[j] = f2bf(v);
        }
        uint4 pk;
        pk.x = (u32)o[0] | ((u32)o[1] << 16);
        pk.y = (u32)o[2] | ((u32)o[3] << 16);
        pk.z = (u32)o[4] | ((u32)o[5] << 16);
        pk.w = (u32)o[6] | ((u32)o[7] << 16);
        *(uint4*)(whhf + (size_t)id * 8) = pk;
    }
    int id2 = id - 23296;
    if (id2 >= 0 && id2 < 13312) { // 52*4*64 lane-slots for wih
        int l = id2 & 63, fi = id2 >> 6;
        int kt = fi & 3, ntg = fi >> 2;
        int n = ntg * 16 + (l & 15);
        int kb = kt * 32 + (l >> 4) * 8;
        u16 o[8];
#pragma unroll
        for (int j = 0; j < 8; ++j) {
            int k = kb + j; // < 128 always
            float v = (n < G1) ? wih1[n * FEAT + k] : 0.f;
            o[j] = f2bf(v);
        }
        uint4 pk;
        pk.x = (u32)o[0] | ((u32)o[1] << 16);
        pk.y = (u32)o[2] | ((u32)o[3] << 16);
        pk.z = (u32)o[4] | ((u32)o[5] << 16);
        pk.w = (u32)o[6] | ((u32)o[7] << 16);
        *(uint4*)(wihf + (size_t)id2 * 8) = pk;
    }
}

// ---------------------------------------------------------------------------
// Kernel 2: xg = X @ W_ih1^T + (b_ih1+b_hh1), stored bf16 in C-fragment order:
//   xg[((t*64 + mw)*52 + ntg)*64 + cl*4 + r]
// Each WG handles 64 M-rows (one quarter of one timestep's batch).
// ---------------------------------------------------------------------------
__global__ __launch_bounds__(256, 1) void xg_gemm(const float* __restrict__ X,
                                                  const u16* __restrict__ wihf,
                                                  const float* __restrict__ b1p,
                                                  u16* __restrict__ xg) {
    __shared__ u16 xs[64 * 128]; // bf16 X tile, XOR-swizzled
    int tid = threadIdx.x, wg = blockIdx.x;
    int l = tid & 63, wv = tid >> 6;
    int arow = l & 15, khi = l >> 4;

    const float4* Xv = (const float4*)(X + (size_t)wg * 64 * 128);
#pragma unroll
    for (int i = 0; i < 8; ++i) {
        int idx = tid + i * 256; // 0..2047
        float4 v = Xv[idx];
        int row = idx >> 5;
        int col = (idx & 31) * 4;
        uint2 pk;
        pk.x = (u32)f2bf(v.x) | ((u32)f2bf(v.y) << 16);
        pk.y = (u32)f2bf(v.z) | ((u32)f2bf(v.w) << 16);
        int byteo = (row * 256 + col * 2) ^ ((row & 7) << 4);
        *(uint2*)((char*)xs + byteo) = pk;
    }
    __syncthreads();

    f32x4 acc[4][13];
#pragma unroll
    for (int mt = 0; mt < 4; ++mt)
#pragma unroll
        for (int nt = 0; nt < 13; ++nt) acc[mt][nt] = (f32x4){0.f, 0.f, 0.f, 0.f};

#pragma unroll
    for (int kt = 0; kt < 4; ++kt) {
        bf16x8 wfr[13];
#pragma unroll
        for (int nt = 0; nt < 13; ++nt) {
            int ntg = wv * 13 + nt;
            wfr[nt] = *(const bf16x8*)(wihf + ((size_t)(ntg * 4 + kt) * 64 + l) * 8);
        }
#pragma unroll
        for (int mt = 0; mt < 4; ++mt) {
            int row = mt * 16 + arow;
            int byteo = (row * 256 + kt * 64 + khi * 16) ^ ((row & 7) << 4);
            bf16x8 a = *(const bf16x8*)((const char*)xs + byteo);
#pragma unroll
            for (int nt = 0; nt < 13; ++nt)
                acc[mt][nt] = __builtin_amdgcn_mfma_f32_16x16x32_bf16(a, wfr[nt], acc[mt][nt], 0, 0, 0);
        }
    }

    int t = wg >> 2;
#pragma unroll
    for (int nt = 0; nt < 13; ++nt) {
        int ntg = wv * 13 + nt;
        int colg = ntg * 16 + arow;
        float bias = b1p[colg];
#pragma unroll
        for (int mt = 0; mt < 4; ++mt) {
            int mwl = (wg & 3) * 16 + mt * 4 + khi;
            u16 r0 = f2bf(acc[mt][nt][0] + bias);
            u16 r1 = f2bf(acc[mt][nt][1] + bias);
            u16 r2 = f2bf(acc[mt][nt][2] + bias);
            u16 r3 = f2bf(acc[mt][nt][3] + bias);
            uint2 pk;
            pk.x = (u32)r0 | ((u32)r1 << 16);
            pk.y = (u32)r2 | ((u32)r3 << 16);
            size_t off = (((size_t)t * 64 + mwl) * 52 + ntg) * 64 + arow * 4;
            *(uint2*)(xg + off) = pk;
        }
    }
}

// ---------------------------------------------------------------------------
// Kernel 3: persistent fused 2-layer LSTM. 64 WGs x 256 threads; WG mw owns
// batch rows [mw*4, mw*4+4). W_hh1 lives in registers (364 VGPR/lane).
// Per step: 91 MFMA -> gates to LDS -> elementwise (c,h) -> fused layer-2.
// Only block-level barriers (3/step).
// gbuf layout: [b][col] (b=batch 0..3, col=raw gate column 0..831) ->
//   writer: 4 conflict-free scalar stores (16 lanes, consecutive cols);
//   reader: stride-1 over j -> conflict-free.
// ---------------------------------------------------------------------------
__global__ __launch_bounds__(256, 1) void lstm_main(const u16* __restrict__ xg,
                                                    const u16* __restrict__ whhf,
                                                    const float* __restrict__ w_ih2,
                                                    const float* __restrict__ w_hh2,
                                                    const float* __restrict__ b_ih2,
                                                    const float* __restrict__ b_hh2,
                                                    float* __restrict__ out) {
    __shared__ u16 hbuf[16 * KP];     // bf16 h, XOR-swizzled, K-padded (7 KiB)
    __shared__ float gbuf[BS * G1P];  // gates [b][col] (13.3 KiB)
    __shared__ float h1f[BS * H1];    // fp32 h for layer-2 dot
    __shared__ float w2s[12 * H1];
    __shared__ float whh2s[36];
    __shared__ float b2s[12];
    __shared__ float g2buf[48];
    __shared__ float h2s[12];
    __shared__ float c2s[12];

    int tid = threadIdx.x, mw = blockIdx.x;
    int l = tid & 63, wv = tid >> 6;
    int arow = l & 15, khi = l >> 4;
    const bool ldx = (l < 16);

    for (int i = tid; i < 12 * H1; i += 256) w2s[i] = w_ih2[i];
    if (tid < 36) whh2s[tid] = w_hh2[tid];
    if (tid < 12) {
        b2s[tid] = b_ih2[tid] + b_hh2[tid];
        h2s[tid] = 0.f;
        c2s[tid] = 0.f;
    }
    for (int i = tid; i < 16 * KP; i += 256) hbuf[i] = 0;

    // persistent recurrent weights in registers
    bf16x8 wf[13][7];
#pragma unroll
    for (int nt = 0; nt < 13; ++nt)
#pragma unroll
        for (int kt = 0; kt < 7; ++kt)
            wf[nt][kt] = *(const bf16x8*)(whhf + ((size_t)((wv * 13 + nt) * 7 + kt) * 64 + l) * 8);

    float creg[4] = {0.f, 0.f, 0.f, 0.f};

    // prefetch xg for t=0
    uint2 xr[13];
#pragma unroll
    for (int nt = 0; nt < 13; ++nt)
        if (ldx) xr[nt] = *(const uint2*)(xg + (((size_t)0 * 64 + mw) * 52 + wv * 13 + nt) * 64 + l * 4);

    __syncthreads();

    for (int t = 0; t < T_STEPS; ++t) {
        // A-fragments of h (bf16, swizzled)
        bf16x8 ha[7];
#pragma unroll
        for (int kt = 0; kt < 7; ++kt) {
            int byteo = (arow * (KP * 2) + kt * 64 + khi * 16) ^ ((arow & 7) << 4);
            ha[kt] = *(const bf16x8*)((const char*)hbuf + byteo);
        }
        // acc init from prefetched xg (rows 0..3 live in lanes 0..15)
        f32x4 acc[13];
#pragma unroll
        for (int nt = 0; nt < 13; ++nt) {
            f32x4 v = {0.f, 0.f, 0.f, 0.f};
            if (ldx) {
                v[0] = bfu2f(xr[nt].x & 0xffffu);
                v[1] = bfu2f(xr[nt].x >> 16);
                v[2] = bfu2f(xr[nt].y & 0xffffu);
                v[3] = bfu2f(xr[nt].y >> 16);
            }
            acc[nt] = v;
        }
        // prefetch next step's xg (hides HBM latency under this step)
        if (t + 1 < T_STEPS && ldx) {
#pragma unroll
            for (int nt = 0; nt < 13; ++nt)
                xr[nt] = *(const uint2*)(xg + (((size_t)(t + 1) * 64 + mw) * 52 + wv * 13 + nt) * 64 + l * 4);
        }
        // recurrent GEMM: gates += h @ W_hh^T
#pragma unroll
        for (int kt = 0; kt < 7; ++kt)
#pragma unroll
            for (int nt = 0; nt < 13; ++nt)
                acc[nt] = __builtin_amdgcn_mfma_f32_16x16x32_bf16(ha[kt], wf[nt][kt], acc[nt], 0, 0, 0);

        if (ldx) {
#pragma unroll
            for (int nt = 0; nt < 13; ++nt) {
                int col = wv * 208 + nt * 16 + arow;
#pragma unroll
                for (int r = 0; r < 4; ++r) gbuf[r * G1P + col] = acc[nt][r];
            }
        }
        __syncthreads(); // b1

        // elementwise layer-1: c,h update (c persistent in registers)
        // gate columns: i=j, f=200+j, g=400+j, o=600+j  (raw weight-row order)
#pragma unroll
        for (int i = 0; i < 4; ++i) {
            int p = tid + (i << 8);
            if (p < G1) {
                int b = p / H1;
                int j = p - b * H1;
                const float* gb = gbuf + b * G1P;
                float gi = sigf(gb[j]);
                float gf = sigf(gb[200 + j]);
                float gg = tanhf_fast(gb[400 + j]);
                float go = sigf(gb[600 + j]);
                float c = gf * creg[i] + gi * gg;
                creg[i] = c;
                float h = go * tanhf_fast(c);
                h1f[b * H1 + j] = h;
                *(u16*)((char*)hbuf + ((b * (KP * 2) + j * 2) ^ (b << 4))) = f2bf(h);
            }
        }
        __syncthreads(); // b2

        // layer-2: 48 dot products, 16 lanes each, 3 rounds
        int lane16 = tid & 15;
#pragma unroll
        for (int rr = 0; rr < 3; ++rr) {
            int d = (tid >> 4) + (rr << 4); // 0..47
            int b = d / 12;
            int g = d - b * 12;
            float s = 0.f;
            for (int k = lane16; k < H1; k += 16) s += w2s[g * H1 + k] * h1f[b * H1 + k];
            if (lane16 < 3) s += whh2s[g * 3 + lane16] * h2s[b * 3 + lane16];
            s += __shfl_xor(s, 8, 16);
            s += __shfl_xor(s, 4, 16);
            s += __shfl_xor(s, 2, 16);
            s += __shfl_xor(s, 1, 16);
            if (lane16 == 0) g2buf[d] = s + b2s[g];
        }
        __syncthreads(); // b3

        // layer-2 elementwise + output store
        if (tid < 12) {
            int b = tid / 3;
            int hh = tid - b * 3;
            float gi = sigf(g2buf[b * 12 + hh]);
            float gf = sigf(g2buf[b * 12 + 3 + hh]);
            float gg = tanhf_fast(g2buf[b * 12 + 6 + hh]);
            float go = sigf(g2buf[b * 12 + 9 + hh]);
            float c = gf * c2s[tid] + gi * gg;
            c2s[tid] = c;
            float h = go * tanhf_fast(c);
            h2s[tid] = h;
            out[(size_t)t * 768 + (mw * 4 + b) * 3 + hh] = h;
        }
    }
}

extern "C" void kernel_launch(void* const* d_in, const int* in_sizes, int n_in,
                              void* d_out, int out_size, void* d_ws, size_t ws_size,
                              hipStream_t stream) {
    const float* X = (const float*)d_in[0];
    const float* w_ih1 = (const float*)d_in[1];
    const float* w_hh1 = (const float*)d_in[2];
    const float* b_ih1 = (const float*)d_in[3];
    const float* b_hh1 = (const float*)d_in[4];
    const float* w_ih2 = (const float*)d_in[5];
    const float* w_hh2 = (const float*)d_in[6];
    const float* b_ih2 = (const float*)d_in[7];
    const float* b_hh2 = (const float*)d_in[8];
    float* out = (float*)d_out;

    char* ws = (char*)d_ws;
    size_t off = 0;
    u16* xg = (u16*)(ws + off);
    off += (size_t)512 * 64 * 52 * 64 * 2; // 218,103,808 B
    u16* whhf = (u16*)(ws + off);
    off += (size_t)23296 * 8 * 2; // 372,736 B
    u16* wihf = (u16*)(ws + off);
    off += (size_t)13312 * 8 * 2; // 212,992 B
    float* b1p = (float*)(ws + off);
    off += 832 * 4;
    if (ws_size < off) return; // insufficient workspace -> visible failure

    repack_k<<<143, 256, 0, stream>>>(w_ih1, w_hh1, b_ih1, b_hh1, wihf, whhf, b1p);
    xg_gemm<<<2048, 256, 0, stream>>>(X, wihf, b1p, xg);
    lstm_main<<<64, 256, 0, stream>>>(xg, whhf, w_ih2, w_hh2, b_ih2, b_hh2, out);
}

// Round 3
// 1358.702 us; speedup vs baseline: 2.9488x; 2.9488x over previous
//
#include <hip/hip_runtime.h>

typedef unsigned short u16;
typedef unsigned int u32;
typedef __attribute__((ext_vector_type(8))) short bf16x8;
typedef __attribute__((ext_vector_type(4))) float f32x4;

#define T_STEPS 512
#define FEAT 128
#define H1 200
#define G1 800
#define G1P 832
#define KP 224

// async global->LDS, 16B per lane; LDS dest = uniform base + lane*16
#define G2L16(g, lp) __builtin_amdgcn_global_load_lds( \
    (const __attribute__((address_space(1))) void*)(g), \
    (__attribute__((address_space(3))) void*)(lp), 16, 0, 0)

__device__ __forceinline__ u16 f2bf(float x) {
    u32 u = __float_as_uint(x);
    u = (u + 0x7fffu + ((u >> 16) & 1u)) >> 16;
    return (u16)u;
}
__device__ __forceinline__ float bfu2f(u32 u) { return __uint_as_float(u << 16); }

// v_exp_f32-based activations (exp2 form): 4-5 VALU each
__device__ __forceinline__ float sig2(float x) {
    return __builtin_amdgcn_rcpf(1.f + __builtin_amdgcn_exp2f(-1.442695041f * x));
}
__device__ __forceinline__ float tanh2(float x) {
    return 1.f - 2.f * __builtin_amdgcn_rcpf(1.f + __builtin_amdgcn_exp2f(2.885390082f * x));
}

// ---------------------------------------------------------------------------
// Kernel 1: repack W_ih1/W_hh1 to bf16 MFMA B-fragment order + fused bias.
// (unchanged from round 2 — verified correct)
// ---------------------------------------------------------------------------
__global__ void repack_k(const float* __restrict__ wih1, const float* __restrict__ whh1,
                         const float* __restrict__ bih1, const float* __restrict__ bhh1,
                         u16* __restrict__ wihf, u16* __restrict__ whhf, float* __restrict__ b1p) {
    int id = blockIdx.x * 256 + threadIdx.x;
    if (id < G1P) b1p[id] = (id < G1) ? (bih1[id] + bhh1[id]) : 0.f;
    if (id < 23296) { // 52*7*64 lane-slots for whh
        int l = id & 63, fi = id >> 6;
        int kt = fi % 7, nti = fi / 7;
        int n = nti * 16 + (l & 15);
        int kb = kt * 32 + (l >> 4) * 8;
        u16 o[8];
#pragma unroll
        for (int j = 0; j < 8; ++j) {
            int k = kb + j;
            float v = (n < G1 && k < H1) ? whh1[n * H1 + k] : 0.f;
            o[j] = f2bf(v);
        }
        uint4 pk;
        pk.x = (u32)o[0] | ((u32)o[1] << 16);
        pk.y = (u32)o[2] | ((u32)o[3] << 16);
        pk.z = (u32)o[4] | ((u32)o[5] << 16);
        pk.w = (u32)o[6] | ((u32)o[7] << 16);
        *(uint4*)(whhf + (size_t)id * 8) = pk;
    }
    int id2 = id - 23296;
    if (id2 >= 0 && id2 < 13312) { // 52*4*64 lane-slots for wih
        int l = id2 & 63, fi = id2 >> 6;
        int kt = fi & 3, ntg = fi >> 2;
        int n = ntg * 16 + (l & 15);
        int kb = kt * 32 + (l >> 4) * 8;
        u16 o[8];
#pragma unroll
        for (int j = 0; j < 8; ++j) {
            int k = kb + j;
            float v = (n < G1) ? wih1[n * FEAT + k] : 0.f;
            o[j] = f2bf(v);
        }
        uint4 pk;
        pk.x = (u32)o[0] | ((u32)o[1] << 16);
        pk.y = (u32)o[2] | ((u32)o[3] << 16);
        pk.z = (u32)o[4] | ((u32)o[5] << 16);
        pk.w = (u32)o[6] | ((u32)o[7] << 16);
        *(uint4*)(wihf + (size_t)id2 * 8) = pk;
    }
}

// ---------------------------------------------------------------------------
// Kernel 2: xg = X @ W_ih1^T + (b_ih1+b_hh1), stored bf16 in NATURAL layout
//   xg[t][batch][col 0..831]  (col = raw gate row: i=j, f=200+j, g=400+j, o=600+j)
// ---------------------------------------------------------------------------
__global__ __launch_bounds__(256, 1) void xg_gemm(const float* __restrict__ X,
                                                  const u16* __restrict__ wihf,
                                                  const float* __restrict__ b1p,
                                                  u16* __restrict__ xg) {
    __shared__ u16 xs[64 * 128]; // bf16 X tile, XOR-swizzled
    int tid = threadIdx.x, wg = blockIdx.x;
    int l = tid & 63, wv = tid >> 6;
    int arow = l & 15, khi = l >> 4;

    const float4* Xv = (const float4*)(X + (size_t)wg * 64 * 128);
#pragma unroll
    for (int i = 0; i < 8; ++i) {
        int idx = tid + i * 256;
        float4 v = Xv[idx];
        int row = idx >> 5;
        int col = (idx & 31) * 4;
        uint2 pk;
        pk.x = (u32)f2bf(v.x) | ((u32)f2bf(v.y) << 16);
        pk.y = (u32)f2bf(v.z) | ((u32)f2bf(v.w) << 16);
        int byteo = (row * 256 + col * 2) ^ ((row & 7) << 4);
        *(uint2*)((char*)xs + byteo) = pk;
    }
    __syncthreads();

    f32x4 acc[4][13];
#pragma unroll
    for (int mt = 0; mt < 4; ++mt)
#pragma unroll
        for (int nt = 0; nt < 13; ++nt) acc[mt][nt] = (f32x4){0.f, 0.f, 0.f, 0.f};

#pragma unroll
    for (int kt = 0; kt < 4; ++kt) {
        bf16x8 wfr[13];
#pragma unroll
        for (int nt = 0; nt < 13; ++nt) {
            int ntg = wv * 13 + nt;
            wfr[nt] = *(const bf16x8*)(wihf + ((size_t)(ntg * 4 + kt) * 64 + l) * 8);
        }
#pragma unroll
        for (int mt = 0; mt < 4; ++mt) {
            int row = mt * 16 + arow;
            int byteo = (row * 256 + kt * 64 + khi * 16) ^ ((row & 7) << 4);
            bf16x8 a = *(const bf16x8*)((const char*)xs + byteo);
#pragma unroll
            for (int nt = 0; nt < 13; ++nt)
                acc[mt][nt] = __builtin_amdgcn_mfma_f32_16x16x32_bf16(a, wfr[nt], acc[mt][nt], 0, 0, 0);
        }
    }

    int t = wg >> 2;
#pragma unroll
    for (int nt = 0; nt < 13; ++nt) {
        int ntg = wv * 13 + nt;
        int colg = ntg * 16 + arow;
        float bias = b1p[colg];
#pragma unroll
        for (int mt = 0; mt < 4; ++mt) {
#pragma unroll
            for (int r = 0; r < 4; ++r) {
                int bg = (wg & 3) * 64 + mt * 16 + khi * 4 + r;
                xg[((size_t)t * 256 + bg) * G1P + colg] = f2bf(acc[mt][nt][r] + bias);
            }
        }
    }
}

// ---------------------------------------------------------------------------
// Kernel 3: persistent fused 2-layer LSTM. 64 WGs x 256 threads (4 waves).
// wave = batch row within WG. W_hh1 resident (364 regs, AGPR-assisted).
// Per step: stage(t+1) async -> 91+7 MFMA -> vmcnt(2)+barrier -> EW (+deferred
// layer-2 EW on wave0) -> barrier -> reload h fragments. 2 barriers/step.
// ---------------------------------------------------------------------------
__global__ __launch_bounds__(256, 1) void lstm_main(const u16* __restrict__ xg,
                                                    const u16* __restrict__ whhf,
                                                    const float* __restrict__ w_ih2,
                                                    const float* __restrict__ w_hh2,
                                                    const float* __restrict__ b_ih2,
                                                    const float* __restrict__ b_hh2,
                                                    float* __restrict__ out) {
    __shared__ __align__(16) u16 hbuf[16 * KP];      // 7168 B, XOR-swizzled bf16 h
    __shared__ __align__(16) float gbuf[4 * G1P];    // 13312 B, gates [b][col]
    __shared__ __align__(16) u16 xgs[2][4096];       // 16384 B, staged xg rows (dbuf)
    __shared__ __align__(16) u16 wf2s[7 * 512];      // 7168 B, layer-2 B-fragments
    __shared__ __align__(16) float g2buf[64];        // layer-2 pre-acts [col][b]
    __shared__ float h2s[12];

    int tid = threadIdx.x, mw = blockIdx.x;
    int l = tid & 63, wv = tid >> 6;
    int arow = l & 15, khi = l >> 4;
    int fb3 = l / 3, fh3 = l - fb3 * 3; // layer-2 lane map (lanes 0..11 of wave0)

    for (int i = tid; i < 16 * KP; i += 256) hbuf[i] = 0;
    if (tid < 12) h2s[tid] = 0.f;

    // wave3: build layer-2 B-fragments (w_ih2, 12x200, bf16) into LDS
    if (wv == 3) {
#pragma unroll
        for (int kt = 0; kt < 7; ++kt) {
            int kb = kt * 32 + khi * 8;
            u16 o[8];
#pragma unroll
            for (int j = 0; j < 8; ++j) {
                int k = kb + j;
                o[j] = (arow < 12 && k < H1) ? f2bf(w_ih2[arow * H1 + k]) : (u16)0;
            }
            uint4 pk;
            pk.x = (u32)o[0] | ((u32)o[1] << 16);
            pk.y = (u32)o[2] | ((u32)o[3] << 16);
            pk.z = (u32)o[4] | ((u32)o[5] << 16);
            pk.w = (u32)o[6] | ((u32)o[7] << 16);
            *(uint4*)((char*)wf2s + kt * 1024 + l * 16) = pk;
        }
    }

    // wave0 lanes<12: layer-2 recurrent weights + fused bias (held in regs)
    float wh[4][3], b2l[4];
    if (wv == 0 && l < 12) {
#pragma unroll
        for (int gt = 0; gt < 4; ++gt) {
            int rw = gt * 3 + fh3;
#pragma unroll
            for (int j = 0; j < 3; ++j) wh[gt][j] = w_hh2[rw * 3 + j];
            b2l[gt] = b_ih2[rw] + b_hh2[rw];
        }
    }

    // persistent recurrent weights (B-fragments)
    bf16x8 wf[13][7];
#pragma unroll
    for (int nt = 0; nt < 13; ++nt)
#pragma unroll
        for (int kt = 0; kt < 7; ++kt)
            wf[nt][kt] = *(const bf16x8*)(whhf + ((size_t)((wv * 13 + nt) * 7 + kt) * 64 + l) * 8);

    float creg[4] = {0.f, 0.f, 0.f, 0.f};
    float c2 = 0.f;
    const f32x4 fz = {0.f, 0.f, 0.f, 0.f};

    __syncthreads(); // pre-loop full barrier (drains everything once)

    // initial h fragments (zeros)
    bf16x8 ha[7];
#pragma unroll
    for (int kt = 0; kt < 7; ++kt) {
        int byteo = (arow * (KP * 2) + kt * 64 + khi * 16) ^ ((arow & 7) << 4);
        ha[kt] = *(const bf16x8*)((const char*)hbuf + byteo);
    }

    // stage xg(t=0) into xgs[0]: 8 chunks of 1024B, 2 per wave
    {
        const char* g0 = (const char*)xg + (size_t)mw * (4 * G1P * 2) + wv * 1024 + l * 16;
        char* ld = (char*)&xgs[0][0] + wv * 1024;
        G2L16(g0, ld);
        G2L16(g0 + 4096, ld + 4096);
    }

    for (int t = 0; t < T_STEPS; ++t) {
        // stage xg(t+1) (async; stays in flight across the barrier)
        {
            const char* g0 = (const char*)xg + ((size_t)(t + 1) * 256 + mw * 4) * (G1P * 2)
                             + wv * 1024 + l * 16;
            char* ld = (char*)&xgs[(t + 1) & 1][0] + wv * 1024;
            G2L16(g0, ld);
            G2L16(g0 + 4096, ld + 4096);
        }

        // recurrent GEMM: gates = h(t-1) @ W_hh^T  (C=0 via hoisted zero regs)
        f32x4 acc[13];
#pragma unroll
        for (int nt = 0; nt < 13; ++nt)
            acc[nt] = __builtin_amdgcn_mfma_f32_16x16x32_bf16(ha[0], wf[nt][0], fz, 0, 0, 0);
#pragma unroll
        for (int kt = 1; kt < 7; ++kt)
#pragma unroll
            for (int nt = 0; nt < 13; ++nt)
                acc[nt] = __builtin_amdgcn_mfma_f32_16x16x32_bf16(ha[kt], wf[nt][kt], acc[nt], 0, 0, 0);

        // wave3: layer-2 pre-acts for step t-1 (reuses ha fragments)
        if (wv == 3) {
            f32x4 acc2 = fz;
#pragma unroll
            for (int kt = 0; kt < 7; ++kt) {
                bf16x8 w2f = *(const bf16x8*)((const char*)wf2s + kt * 1024 + l * 16);
                acc2 = __builtin_amdgcn_mfma_f32_16x16x32_bf16(ha[kt], w2f, acc2, 0, 0, 0);
            }
            if (l < 16) *(f32x4*)&g2buf[l * 4] = acc2;
        }

        // gate stores: [b][col], 16 lanes, conflict-free
        if (l < 16) {
#pragma unroll
            for (int nt = 0; nt < 13; ++nt) {
                int col = wv * 208 + nt * 16 + arow;
#pragma unroll
                for (int r = 0; r < 4; ++r) gbuf[r * G1P + col] = acc[nt][r];
            }
        }

        asm volatile("s_waitcnt vmcnt(2)" ::: "memory");   // xg(t) arrived; t+1 in flight
        asm volatile("s_waitcnt lgkmcnt(0)" ::: "memory");
        __builtin_amdgcn_s_barrier(); // b1

        // layer-1 elementwise: wave handles batch row b = wv, j in [0,200)
        {
            const float* gb = &gbuf[wv * G1P];
            const u16* xr = &xgs[t & 1][wv * G1P];
#pragma unroll
            for (int r = 0; r < 4; ++r) {
                int j = r * 64 + l;
                if (j < H1) {
                    float pi = gb[j] + bfu2f(xr[j]);
                    float pf = gb[H1 + j] + bfu2f(xr[H1 + j]);
                    float pg = gb[2 * H1 + j] + bfu2f(xr[2 * H1 + j]);
                    float po = gb[3 * H1 + j] + bfu2f(xr[3 * H1 + j]);
                    float gi = sig2(pi), gf = sig2(pf), gg = tanh2(pg), go = sig2(po);
                    float c = gf * creg[r] + gi * gg;
                    creg[r] = c;
                    float h = go * tanh2(c);
                    *(u16*)((char*)hbuf + ((wv * (KP * 2) + j * 2) ^ (wv << 4))) = f2bf(h);
                }
            }
        }

        // wave0: layer-2 elementwise for step t-1 (pipelined one step behind)
        if (wv == 0 && l < 12 && t > 0) {
            float hp0 = h2s[fb3 * 3 + 0], hp1 = h2s[fb3 * 3 + 1], hp2 = h2s[fb3 * 3 + 2];
            float p0 = g2buf[(0 + fh3) * 4 + fb3] + b2l[0] + wh[0][0] * hp0 + wh[0][1] * hp1 + wh[0][2] * hp2;
            float p1 = g2buf[(3 + fh3) * 4 + fb3] + b2l[1] + wh[1][0] * hp0 + wh[1][1] * hp1 + wh[1][2] * hp2;
            float p2 = g2buf[(6 + fh3) * 4 + fb3] + b2l[2] + wh[2][0] * hp0 + wh[2][1] * hp1 + wh[2][2] * hp2;
            float p3 = g2buf[(9 + fh3) * 4 + fb3] + b2l[3] + wh[3][0] * hp0 + wh[3][1] * hp1 + wh[3][2] * hp2;
            float i2 = sig2(p0), f2v = sig2(p1), g2v = tanh2(p2), o2 = sig2(p3);
            c2 = f2v * c2 + i2 * g2v;
            float h2v = o2 * tanh2(c2);
            h2s[l] = h2v;
            out[(size_t)(t - 1) * 768 + (mw * 4 + fb3) * 3 + fh3] = h2v;
        }

        asm volatile("s_waitcnt lgkmcnt(0)" ::: "memory");
        __builtin_amdgcn_s_barrier(); // b2

        // h fragments for next step (also feeds wave3's next layer-2 MFMA)
#pragma unroll
        for (int kt = 0; kt < 7; ++kt) {
            int byteo = (arow * (KP * 2) + kt * 64 + khi * 16) ^ ((arow & 7) << 4);
            ha[kt] = *(const bf16x8*)((const char*)hbuf + byteo);
        }
    }

    // epilogue: layer-2 for step 511
    asm volatile("s_waitcnt vmcnt(0)" ::: "memory"); // drain dangling stage(512)
    if (wv == 3) {
        f32x4 acc2 = fz;
#pragma unroll
        for (int kt = 0; kt < 7; ++kt) {
            bf16x8 w2f = *(const bf16x8*)((const char*)wf2s + kt * 1024 + l * 16);
            acc2 = __builtin_amdgcn_mfma_f32_16x16x32_bf16(ha[kt], w2f, acc2, 0, 0, 0);
        }
        if (l < 16) *(f32x4*)&g2buf[l * 4] = acc2;
    }
    asm volatile("s_waitcnt lgkmcnt(0)" ::: "memory");
    __builtin_amdgcn_s_barrier();
    if (wv == 0 && l < 12) {
        float hp0 = h2s[fb3 * 3 + 0], hp1 = h2s[fb3 * 3 + 1], hp2 = h2s[fb3 * 3 + 2];
        float p0 = g2buf[(0 + fh3) * 4 + fb3] + b2l[0] + wh[0][0] * hp0 + wh[0][1] * hp1 + wh[0][2] * hp2;
        float p1 = g2buf[(3 + fh3) * 4 + fb3] + b2l[1] + wh[1][0] * hp0 + wh[1][1] * hp1 + wh[1][2] * hp2;
        float p2 = g2buf[(6 + fh3) * 4 + fb3] + b2l[2] + wh[2][0] * hp0 + wh[2][1] * hp1 + wh[2][2] * hp2;
        float p3 = g2buf[(9 + fh3) * 4 + fb3] + b2l[3] + wh[3][0] * hp0 + wh[3][1] * hp1 + wh[3][2] * hp2;
        float i2 = sig2(p0), f2v = sig2(p1), g2v = tanh2(p2), o2 = sig2(p3);
        c2 = f2v * c2 + i2 * g2v;
        float h2v = o2 * tanh2(c2);
        out[(size_t)511 * 768 + (mw * 4 + fb3) * 3 + fh3] = h2v;
    }
}

extern "C" void kernel_launch(void* const* d_in, const int* in_sizes, int n_in,
                              void* d_out, int out_size, void* d_ws, size_t ws_size,
                              hipStream_t stream) {
    const float* X = (const float*)d_in[0];
    const float* w_ih1 = (const float*)d_in[1];
    const float* w_hh1 = (const float*)d_in[2];
    const float* b_ih1 = (const float*)d_in[3];
    const float* b_hh1 = (const float*)d_in[4];
    const float* w_ih2 = (const float*)d_in[5];
    const float* w_hh2 = (const float*)d_in[6];
    const float* b_ih2 = (const float*)d_in[7];
    const float* b_hh2 = (const float*)d_in[8];
    float* out = (float*)d_out;

    char* ws = (char*)d_ws;
    size_t off = 0;
    u16* xg = (u16*)(ws + off);
    off += (size_t)512 * 256 * G1P * 2; // 218,103,808 B (natural layout)
    u16* whhf = (u16*)(ws + off);
    off += (size_t)23296 * 8 * 2; // 372,736 B (also absorbs stage overread)
    u16* wihf = (u16*)(ws + off);
    off += (size_t)13312 * 8 * 2; // 212,992 B
    float* b1p = (float*)(ws + off);
    off += 832 * 4;
    if (ws_size < off) return; // insufficient workspace -> visible failure

    repack_k<<<143, 256, 0, stream>>>(w_ih1, w_hh1, b_ih1, b_hh1, wihf, whhf, b1p);
    xg_gemm<<<2048, 256, 0, stream>>>(X, wihf, b1p, xg);
    lstm_main<<<64, 256, 0, stream>>>(xg, whhf, w_ih2, w_hh2, b_ih2, b_hh2, out);
}

// Round 4
// 1138.517 us; speedup vs baseline: 3.5191x; 1.1934x over previous
//
#include <hip/hip_runtime.h>

typedef unsigned short u16;
typedef unsigned int u32;
typedef __attribute__((ext_vector_type(8))) short bf16x8;
typedef __attribute__((ext_vector_type(4))) float f32x4;

#define T_STEPS 512
#define FEAT 128
#define H1 200
#define G1 800
#define G1P 832
#define KP 224
#define NTILE 50
#define XG_T_BYTES 425984   // 256 * 832 * 2
#define XG_WG_BYTES 6656    // 4 * 832 * 2

// async global->LDS, 16B/lane; LDS dest must be wave-uniform base (+lane*16 in HW)
#define G2L16(g, lp) __builtin_amdgcn_global_load_lds( \
    (const __attribute__((address_space(1))) void*)(g), \
    (__attribute__((address_space(3))) void*)(lp), 16, 0, 0)

__device__ __forceinline__ u16 f2bf(float x) {
    u32 u = __float_as_uint(x);
    u = (u + 0x7fffu + ((u >> 16) & 1u)) >> 16;
    return (u16)u;
}
__device__ __forceinline__ float bfu2f(u32 u) { return __uint_as_float(u << 16); }

__device__ __forceinline__ float sig2(float x) {
    return __builtin_amdgcn_rcpf(1.f + __builtin_amdgcn_exp2f(-1.442695041f * x));
}
__device__ __forceinline__ float tanh2(float x) {
    return 1.f - 2.f * __builtin_amdgcn_rcpf(1.f + __builtin_amdgcn_exp2f(2.885390082f * x));
}

// ---------------------------------------------------------------------------
// Kernel 1: repack weights to bf16 MFMA B-fragment order + fused bias.
//   whhf: [tile*7+kt][lane][8], tile in [0,50): n = tile*16 + (l&15) (< 800),
//         k = kt*32 + (l>>4)*8 + j, zero-padded for k >= 200
//   wihf: [ntg*4+kt][lane][8]  (52-tile layout, consumed by xg_gemm only)
// ---------------------------------------------------------------------------
__global__ void repack_k(const float* __restrict__ wih1, const float* __restrict__ whh1,
                         const float* __restrict__ bih1, const float* __restrict__ bhh1,
                         u16* __restrict__ wihf, u16* __restrict__ whhf, float* __restrict__ b1p) {
    int id = blockIdx.x * 256 + threadIdx.x;
    if (id < G1P) b1p[id] = (id < G1) ? (bih1[id] + bhh1[id]) : 0.f;
    if (id < 22400) { // 50*7*64 lane-slots for whh
        int l = id & 63, fi = id >> 6;
        int kt = fi % 7, tile = fi / 7;
        int n = tile * 16 + (l & 15);
        int kb = kt * 32 + (l >> 4) * 8;
        u16 o[8];
#pragma unroll
        for (int j = 0; j < 8; ++j) {
            int k = kb + j;
            float v = (k < H1) ? whh1[n * H1 + k] : 0.f;
            o[j] = f2bf(v);
        }
        uint4 pk;
        pk.x = (u32)o[0] | ((u32)o[1] << 16);
        pk.y = (u32)o[2] | ((u32)o[3] << 16);
        pk.z = (u32)o[4] | ((u32)o[5] << 16);
        pk.w = (u32)o[6] | ((u32)o[7] << 16);
        *(uint4*)(whhf + (size_t)id * 8) = pk;
    }
    int id2 = id - 22400;
    if (id2 >= 0 && id2 < 13312) { // 52*4*64 lane-slots for wih
        int l = id2 & 63, fi = id2 >> 6;
        int kt = fi & 3, ntg = fi >> 2;
        int n = ntg * 16 + (l & 15);
        int kb = kt * 32 + (l >> 4) * 8;
        u16 o[8];
#pragma unroll
        for (int j = 0; j < 8; ++j) {
            int k = kb + j;
            float v = (n < G1) ? wih1[n * FEAT + k] : 0.f;
            o[j] = f2bf(v);
        }
        uint4 pk;
        pk.x = (u32)o[0] | ((u32)o[1] << 16);
        pk.y = (u32)o[2] | ((u32)o[3] << 16);
        pk.z = (u32)o[4] | ((u32)o[5] << 16);
        pk.w = (u32)o[6] | ((u32)o[7] << 16);
        *(uint4*)(wihf + (size_t)id2 * 8) = pk;
    }
}

// ---------------------------------------------------------------------------
// Kernel 2: xg = X @ W_ih1^T + (b_ih1+b_hh1), stored bf16, natural layout
//   xg[t][batch][col 0..831]  (col = raw gate row: i=j, f=200+j, g=400+j, o=600+j)
// (verbatim from round 3 — verified)
// ---------------------------------------------------------------------------
__global__ __launch_bounds__(256, 1) void xg_gemm(const float* __restrict__ X,
                                                  const u16* __restrict__ wihf,
                                                  const float* __restrict__ b1p,
                                                  u16* __restrict__ xg) {
    __shared__ u16 xs[64 * 128];
    int tid = threadIdx.x, wg = blockIdx.x;
    int l = tid & 63, wv = tid >> 6;
    int arow = l & 15, khi = l >> 4;

    const float4* Xv = (const float4*)(X + (size_t)wg * 64 * 128);
#pragma unroll
    for (int i = 0; i < 8; ++i) {
        int idx = tid + i * 256;
        float4 v = Xv[idx];
        int row = idx >> 5;
        int col = (idx & 31) * 4;
        uint2 pk;
        pk.x = (u32)f2bf(v.x) | ((u32)f2bf(v.y) << 16);
        pk.y = (u32)f2bf(v.z) | ((u32)f2bf(v.w) << 16);
        int byteo = (row * 256 + col * 2) ^ ((row & 7) << 4);
        *(uint2*)((char*)xs + byteo) = pk;
    }
    __syncthreads();

    f32x4 acc[4][13];
#pragma unroll
    for (int mt = 0; mt < 4; ++mt)
#pragma unroll
        for (int nt = 0; nt < 13; ++nt) acc[mt][nt] = (f32x4){0.f, 0.f, 0.f, 0.f};

#pragma unroll
    for (int kt = 0; kt < 4; ++kt) {
        bf16x8 wfr[13];
#pragma unroll
        for (int nt = 0; nt < 13; ++nt) {
            int ntg = wv * 13 + nt;
            wfr[nt] = *(const bf16x8*)(wihf + ((size_t)(ntg * 4 + kt) * 64 + l) * 8);
        }
#pragma unroll
        for (int mt = 0; mt < 4; ++mt) {
            int row = mt * 16 + arow;
            int byteo = (row * 256 + kt * 64 + khi * 16) ^ ((row & 7) << 4);
            bf16x8 a = *(const bf16x8*)((const char*)xs + byteo);
#pragma unroll
            for (int nt = 0; nt < 13; ++nt)
                acc[mt][nt] = __builtin_amdgcn_mfma_f32_16x16x32_bf16(a, wfr[nt], acc[mt][nt], 0, 0, 0);
        }
    }

    int t = wg >> 2;
#pragma unroll
    for (int nt = 0; nt < 13; ++nt) {
        int ntg = wv * 13 + nt;
        int colg = ntg * 16 + arow;
        float bias = b1p[colg];
#pragma unroll
        for (int mt = 0; mt < 4; ++mt) {
#pragma unroll
            for (int r = 0; r < 4; ++r) {
                int bg = (wg & 3) * 64 + mt * 16 + khi * 4 + r;
                xg[((size_t)t * 256 + bg) * G1P + colg] = f2bf(acc[mt][nt][r] + bias);
            }
        }
    }
}

// ---------------------------------------------------------------------------
// Kernel 3: persistent fused 2-layer LSTM. 64 WGs x 512 threads (8 waves).
// Gate-column tiles {7,7,7,6,6,6,6,5} per wave (50 tiles = 800 cols); wf in
// VGPRs only (<=196/wave), target 2 waves/SIMD. Waves 3-6 stage xg (counted
// vmcnt(2)); wave 7 owns fused layer-2 fully in-register. 2 barriers/step.
// ---------------------------------------------------------------------------
#define LDHB(KT) (*(const bf16x8*)((const char*)hbuf + ((arow * 448 + (KT) * 64 + khi * 16) ^ ((arow & 7) << 4))))

#define MFSTEP0(H) do { \
    _Pragma("unroll") for (int nt_ = 0; nt_ < CNT; ++nt_) \
        acc[nt_] = __builtin_amdgcn_mfma_f32_16x16x32_bf16(H, wf[nt_][0], fz, 0, 0, 0); \
    if constexpr (MODE == 2) acc2 = __builtin_amdgcn_mfma_f32_16x16x32_bf16(H, wf2[0], fz, 0, 0, 0); \
} while (0)

#define MFSTEP(H, KT) do { \
    _Pragma("unroll") for (int nt_ = 0; nt_ < CNT; ++nt_) \
        acc[nt_] = __builtin_amdgcn_mfma_f32_16x16x32_bf16(H, wf[nt_][KT], acc[nt_], 0, 0, 0); \
    if constexpr (MODE == 2) acc2 = __builtin_amdgcn_mfma_f32_16x16x32_bf16(H, wf2[KT], acc2, 0, 0, 0); \
} while (0)

template<int CNT, int MODE>  // MODE: 0 plain, 1 stager, 2 layer-2 owner
__device__ __forceinline__ void lstm_body(
    int tile0, int wv, int l, int mw,
    const u16* __restrict__ xg, const u16* __restrict__ whhf,
    const float* __restrict__ w_ih2, const float* __restrict__ w_hh2,
    const float* __restrict__ b_ih2, const float* __restrict__ b_hh2,
    float* __restrict__ out, u16* hbuf, float* gbuf, u16* xgs)
{
    const int arow = l & 15, khi = l >> 4;
    const int rw = wv >> 1, jbase = (wv & 1) * 100;
    const f32x4 fz = {0.f, 0.f, 0.f, 0.f};

    // persistent W_hh B-fragments (VGPR only)
    bf16x8 wf[CNT][7];
#pragma unroll
    for (int nt = 0; nt < CNT; ++nt)
#pragma unroll
        for (int kt = 0; kt < 7; ++kt)
            wf[nt][kt] = *(const bf16x8*)(whhf + ((size_t)((tile0 + nt) * 7 + kt) * 64 + l) * 8);

    // layer-2 state (wave 7 only; dead code elsewhere)
    bf16x8 wf2[7];
    float wh[4][3], b2l[4], h2p[4], c2[4];
    f32x4 acc2 = fz;
    if constexpr (MODE == 2) {
#pragma unroll
        for (int kt = 0; kt < 7; ++kt) {
            u16 o[8];
#pragma unroll
            for (int j = 0; j < 8; ++j) {
                int k = kt * 32 + khi * 8 + j;
                o[j] = (arow < 12 && k < H1) ? f2bf(w_ih2[arow * H1 + k]) : (u16)0;
            }
            uint4 pk;
            pk.x = (u32)o[0] | ((u32)o[1] << 16);
            pk.y = (u32)o[2] | ((u32)o[3] << 16);
            pk.z = (u32)o[4] | ((u32)o[5] << 16);
            pk.w = (u32)o[6] | ((u32)o[7] << 16);
            wf2[kt] = *(bf16x8*)&pk;
        }
        int hs = (l < 3) ? l : 0;
#pragma unroll
        for (int g = 0; g < 4; ++g) {
#pragma unroll
            for (int q = 0; q < 3; ++q) wh[g][q] = w_hh2[(g * 3 + hs) * 3 + q];
            b2l[g] = b_ih2[g * 3 + hs] + b_hh2[g * 3 + hs];
        }
#pragma unroll
        for (int r = 0; r < 4; ++r) { h2p[r] = 0.f; c2[r] = 0.f; }
    }

    float creg0 = 0.f, creg1 = 0.f;

    // layer-2 elementwise: lanes 0-2 (hh = lane), batch rows in regs; shfl-based
    auto L2EW = [&](int tout) {
        int hs = (l < 3) ? l : 0;
#pragma unroll
        for (int r = 0; r < 4; ++r) {
            float pi = __shfl(acc2[r], hs);
            float pf = __shfl(acc2[r], 3 + hs);
            float pg = __shfl(acc2[r], 6 + hs);
            float po = __shfl(acc2[r], 9 + hs);
            float hq0 = __shfl(h2p[r], 0);
            float hq1 = __shfl(h2p[r], 1);
            float hq2 = __shfl(h2p[r], 2);
            pi += b2l[0] + wh[0][0] * hq0 + wh[0][1] * hq1 + wh[0][2] * hq2;
            pf += b2l[1] + wh[1][0] * hq0 + wh[1][1] * hq1 + wh[1][2] * hq2;
            pg += b2l[2] + wh[2][0] * hq0 + wh[2][1] * hq1 + wh[2][2] * hq2;
            po += b2l[3] + wh[3][0] * hq0 + wh[3][1] * hq1 + wh[3][2] * hq2;
            float gi = sig2(pi), gf = sig2(pf), gg = tanh2(pg), go = sig2(po);
            c2[r] = gf * c2[r] + gi * gg;
            h2p[r] = go * tanh2(c2[r]);
            if (l < 3) out[(size_t)tout * 768 + (mw * 4 + r) * 3 + l] = h2p[r];
        }
    };

    // staging source pointer (waves 3-6): 104 slots each (64 + 40)
    const char* sp = (const char*)xg + (size_t)mw * XG_WG_BYTES + (size_t)(wv - 3) * 1664;
    if constexpr (MODE == 1) {
        char* d = (char*)xgs + (wv - 3) * 1664;  // buf 0
        G2L16(sp + (size_t)l * 16, d);
        if (l < 40) G2L16(sp + 1024 + (size_t)l * 16, d + 1024);
        sp += XG_T_BYTES;
    }

    f32x4 acc[CNT];
    for (int t = 0; t < T_STEPS; ++t) {
        // h(t-1) fragment rotation start (3-deep)
        bf16x8 ha0 = LDHB(0), ha1 = LDHB(1), ha2 = LDHB(2);

        if constexpr (MODE == 1) {
            char* d = (char*)xgs + ((t + 1) & 1) * 6656 + (wv - 3) * 1664;
            G2L16(sp + (size_t)l * 16, d);
            if (l < 40) G2L16(sp + 1024 + (size_t)l * 16, d + 1024);
            sp += XG_T_BYTES;
        }
        if constexpr (MODE == 2) {
            if (t >= 2) L2EW(t - 2);  // overlaps other waves' stage + MFMA start
        }

        MFSTEP0(ha0); ha0 = LDHB(3);
        MFSTEP(ha1, 1); ha1 = LDHB(4);
        MFSTEP(ha2, 2); ha2 = LDHB(5);
        MFSTEP(ha0, 3); ha0 = LDHB(6);
        MFSTEP(ha1, 4);
        MFSTEP(ha2, 5);
        MFSTEP(ha0, 6);

        // gate stores: lanes<16, stride-1 cols, conflict-free
        if (l < 16) {
#pragma unroll
            for (int nt = 0; nt < CNT; ++nt)
#pragma unroll
                for (int r = 0; r < 4; ++r)
                    gbuf[r * G1P + (tile0 + nt) * 16 + l] = acc[nt][r];
        }

        if constexpr (MODE == 1) asm volatile("s_waitcnt vmcnt(2)" ::: "memory");
        asm volatile("s_waitcnt lgkmcnt(0)" ::: "memory");
        __builtin_amdgcn_s_barrier(); // b1

        // layer-1 elementwise: wave -> (row rw, cols jbase..jbase+100)
        {
            const float* gb = gbuf + rw * G1P + jbase;
            const u16* xr = xgs + (t & 1) * 3328 + rw * G1P + jbase;
            float p0[4], p1[4];
#pragma unroll
            for (int g = 0; g < 4; ++g) p0[g] = gb[g * 200 + l] + bfu2f(xr[g * 200 + l]);
#pragma unroll
            for (int g = 0; g < 4; ++g) p1[g] = gb[g * 200 + 64 + l] + bfu2f(xr[g * 200 + 64 + l]);
            {
                float gi = sig2(p0[0]), gf = sig2(p0[1]), gg = tanh2(p0[2]), go = sig2(p0[3]);
                creg0 = gf * creg0 + gi * gg;
                float h = go * tanh2(creg0);
                *(u16*)((char*)hbuf + ((rw * 448 + (jbase + l) * 2) ^ ((rw & 7) << 4))) = f2bf(h);
            }
            if (l < 36) {
                float gi = sig2(p1[0]), gf = sig2(p1[1]), gg = tanh2(p1[2]), go = sig2(p1[3]);
                creg1 = gf * creg1 + gi * gg;
                float h = go * tanh2(creg1);
                *(u16*)((char*)hbuf + ((rw * 448 + (jbase + 64 + l) * 2) ^ ((rw & 7) << 4))) = f2bf(h);
            }
        }

        asm volatile("s_waitcnt lgkmcnt(0)" ::: "memory");
        __builtin_amdgcn_s_barrier(); // b2
    }

    // epilogue (wave 7): finish steps 510 and 511 of layer 2
    if constexpr (MODE == 2) {
        L2EW(510);
        acc2 = __builtin_amdgcn_mfma_f32_16x16x32_bf16(LDHB(0), wf2[0], fz, 0, 0, 0);
        acc2 = __builtin_amdgcn_mfma_f32_16x16x32_bf16(LDHB(1), wf2[1], acc2, 0, 0, 0);
        acc2 = __builtin_amdgcn_mfma_f32_16x16x32_bf16(LDHB(2), wf2[2], acc2, 0, 0, 0);
        acc2 = __builtin_amdgcn_mfma_f32_16x16x32_bf16(LDHB(3), wf2[3], acc2, 0, 0, 0);
        acc2 = __builtin_amdgcn_mfma_f32_16x16x32_bf16(LDHB(4), wf2[4], acc2, 0, 0, 0);
        acc2 = __builtin_amdgcn_mfma_f32_16x16x32_bf16(LDHB(5), wf2[5], acc2, 0, 0, 0);
        acc2 = __builtin_amdgcn_mfma_f32_16x16x32_bf16(LDHB(6), wf2[6], acc2, 0, 0, 0);
        L2EW(511);
    }
}

__global__ __launch_bounds__(512, 2) void lstm_main(const u16* __restrict__ xg,
                                                    const u16* __restrict__ whhf,
                                                    const float* __restrict__ w_ih2,
                                                    const float* __restrict__ w_hh2,
                                                    const float* __restrict__ b_ih2,
                                                    const float* __restrict__ b_hh2,
                                                    float* __restrict__ out) {
    __shared__ __align__(16) u16 hbuf[16 * KP];      // 7168 B, XOR-swizzled bf16 h
    __shared__ __align__(16) float gbuf[4 * G1P];    // 13312 B, gates [b][col]
    __shared__ __align__(16) u16 xgs[2 * 3328];      // 13312 B, staged xg (dbuf)

    int tid = threadIdx.x, mw = blockIdx.x;
    int l = tid & 63, wv = tid >> 6;

    for (int i = tid; i < 16 * KP; i += 512) hbuf[i] = 0;
    __syncthreads();

    if (wv < 3)
        lstm_body<7, 0>(wv * 7, wv, l, mw, xg, whhf, w_ih2, w_hh2, b_ih2, b_hh2, out, hbuf, gbuf, xgs);
    else if (wv < 7)
        lstm_body<6, 1>(21 + (wv - 3) * 6, wv, l, mw, xg, whhf, w_ih2, w_hh2, b_ih2, b_hh2, out, hbuf, gbuf, xgs);
    else
        lstm_body<5, 2>(45, wv, l, mw, xg, whhf, w_ih2, w_hh2, b_ih2, b_hh2, out, hbuf, gbuf, xgs);
}

extern "C" void kernel_launch(void* const* d_in, const int* in_sizes, int n_in,
                              void* d_out, int out_size, void* d_ws, size_t ws_size,
                              hipStream_t stream) {
    const float* X = (const float*)d_in[0];
    const float* w_ih1 = (const float*)d_in[1];
    const float* w_hh1 = (const float*)d_in[2];
    const float* b_ih1 = (const float*)d_in[3];
    const float* b_hh1 = (const float*)d_in[4];
    const float* w_ih2 = (const float*)d_in[5];
    const float* w_hh2 = (const float*)d_in[6];
    const float* b_ih2 = (const float*)d_in[7];
    const float* b_hh2 = (const float*)d_in[8];
    float* out = (float*)d_out;

    char* ws = (char*)d_ws;
    size_t off = 0;
    u16* xg = (u16*)(ws + off);
    off += (size_t)512 * 256 * G1P * 2; // 218,103,808 B (natural layout)
    u16* whhf = (u16*)(ws + off);
    off += (size_t)22400 * 8 * 2; // 358,400 B (also absorbs t=512 stage overread)
    u16* wihf = (u16*)(ws + off);
    off += (size_t)13312 * 8 * 2; // 212,992 B
    float* b1p = (float*)(ws + off);
    off += G1P * 4;
    if (ws_size < off) return; // insufficient workspace -> visible failure

    repack_k<<<140, 256, 0, stream>>>(w_ih1, w_hh1, b_ih1, b_hh1, wihf, whhf, b1p);
    xg_gemm<<<2048, 256, 0, stream>>>(X, wihf, b1p, xg);
    lstm_main<<<64, 512, 0, stream>>>(xg, whhf, w_ih2, w_hh2, b_ih2, b_hh2, out);
}